// Round 1
// baseline (679.733 us; speedup 1.0000x reference)
//
#include <hip/hip_runtime.h>

// GraphTransformerLayer fused pipeline for MI355X (gfx950).
// Shapes: T=64, B=32, E=512, F=2048, H=8, Dh=64, TB=T*B=2048 rows.
//
// Pipeline:
//  1. prep        : fp32->bf16 convert x + all weights into MFMA fragment-linear layouts
//  2. gemm qkv    : (2048x1536x512)  x_b @ in_w^T + in_b -> qkv fp32
//  3. relw        : FUSED rel-projection (131072x1024x512 bf16 MFMA) + score
//                   w[i,j,bh] = s^2 * sum_dh (q+ra)(k+rb), never materializing r
//  4. attn        : softmax over j + attn = w~ @ v  -> attn bf16
//  5. gemm outproj: (2048x512x512) + out_b -> opre fp32
//  6. ln1         : LN(x + opre) -> h fp32 + h bf16
//  7. gemm fc1    : (2048x2048x512) + fc1_b, ReLU -> f bf16
//  8. gemm fc2    : (2048x512x2048) + fc2_b -> f2o fp32
//  9. ln2         : LN(h + f2o) -> d_out fp32

typedef __bf16 bf16;
typedef __attribute__((ext_vector_type(8))) __bf16 bf16x8;
typedef __attribute__((ext_vector_type(4))) __bf16 bf16x4;
typedef __attribute__((ext_vector_type(4))) float f32x4;
typedef __attribute__((ext_vector_type(8))) short s16x8;

// ---------------------------------------------------------------- prep ----
// Fragment-linear layout for a (K,N) operand B[k][n]:
//   elem d: frag = d>>9 (512 elems = one 16x32 n-tile x k-tile block),
//   lane = (d>>3)&63, j = d&7, kt = frag/NT, nt = frag%NT,
//   k = kt*32 + (lane>>4)*8 + j, n = nt*16 + (lane&15).
// MFMA B-frag read is then a contiguous 16B per lane.

__device__ inline void fl_decode(int d, int NT, int& k, int& n) {
  int frag = d >> 9; int lane = (d >> 3) & 63; int j = d & 7;
  int kt = frag / NT, nt = frag - kt * NT;
  k = kt * 32 + ((lane >> 4) << 3) + j;
  n = nt * 16 + (lane & 15);
}

__global__ void prep_kernel(const float* __restrict__ x,
                            const float* __restrict__ in_w,
                            const float* __restrict__ rel_w,
                            const float* __restrict__ out_w,
                            const float* __restrict__ fc1_w,
                            const float* __restrict__ fc2_w,
                            bf16* __restrict__ x_b,
                            bf16* __restrict__ inw_fl,
                            bf16* __restrict__ relw_fl,
                            bf16* __restrict__ outw_fl,
                            bf16* __restrict__ fc1w_fl,
                            bf16* __restrict__ fc2w_fl) {
  int tid = blockIdx.x * 256 + threadIdx.x;
  int k, n;
  if (tid < 1048576) { x_b[tid] = (bf16)x[tid]; return; }
  tid -= 1048576;
  if (tid < 786432) {  // in_w is (N=1536, K=512) row-major: B[k][n] = in_w[n*512+k]
    fl_decode(tid, 96, k, n);
    inw_fl[tid] = (bf16)in_w[n * 512 + k];
    return;
  }
  tid -= 786432;
  if (tid < 524288) {  // rel_w (K=512, N=1024)
    fl_decode(tid, 64, k, n);
    relw_fl[tid] = (bf16)rel_w[k * 1024 + n];
    return;
  }
  tid -= 524288;
  if (tid < 262144) {  // out_w (512,512)
    fl_decode(tid, 32, k, n);
    outw_fl[tid] = (bf16)out_w[k * 512 + n];
    return;
  }
  tid -= 262144;
  if (tid < 1048576) {  // fc1_w (512,2048)
    fl_decode(tid, 128, k, n);
    fc1w_fl[tid] = (bf16)fc1_w[k * 2048 + n];
    return;
  }
  tid -= 1048576;
  if (tid < 1048576) {  // fc2_w (2048,512)
    fl_decode(tid, 32, k, n);
    fc2w_fl[tid] = (bf16)fc2_w[k * 512 + n];
  }
}

// ---------------------------------------------------------------- gemm ----
// Generic bf16 MFMA GEMM. A row-major (M,K) bf16. B fragment-linear bf16.
// C = A@B + bias, optional ReLU, fp32 and/or bf16 outputs.
// Block: 256 thr = 4 waves (2x2), tile 128x128, BK=32. Single-buffered LDS,
// frag-linear LDS layout (conflict-free l*16 reads).
template <bool RELU, bool WF32, bool WBF16>
__global__ __launch_bounds__(256, 2) void gemm_bf16(
    const bf16* __restrict__ A, const bf16* __restrict__ Bfl,
    const float* __restrict__ bias, float* __restrict__ Cf,
    bf16* __restrict__ Cb, int M, int N, int K) {
  __shared__ bf16 lA[4096];
  __shared__ bf16 lB[4096];
  const int tid = threadIdx.x;
  const int l = tid & 63;
  const int wv = tid >> 6;
  const int wm = wv >> 1, wn = wv & 1;
  const int m0 = blockIdx.x * 128, n0 = blockIdx.y * 128;
  const int NT = N >> 4;
  const int nb0 = n0 >> 4;
  const int KT = K >> 5;

  f32x4 acc[4][4];
#pragma unroll
  for (int i = 0; i < 4; i++)
#pragma unroll
    for (int j = 0; j < 4; j++) acc[i][j] = (f32x4)0.f;

  const int c = tid >> 5;          // A chunk (=frag) 0..7
  const int lp0 = (tid & 31) * 2;  // lane-slot base within chunk

  for (int kt = 0; kt < KT; ++kt) {
    // stage A (8KB) into fragment-linear LDS
#pragma unroll
    for (int u = 0; u < 2; ++u) {
      int lp = lp0 + u;
      int row = c * 16 + (lp & 15);
      int kof = (lp >> 4) << 3;
      s16x8 va = *(const s16x8*)(A + (long)(m0 + row) * K + kt * 32 + kof);
      *(s16x8*)(&lA[c * 512 + lp * 8]) = va;
    }
    // stage B (8KB): source already fragment-linear -> straight copy
    {
      const s16x8* src = (const s16x8*)(Bfl + (long)(kt * NT + nb0) * 512);
      s16x8* dst = (s16x8*)lB;
      dst[tid] = src[tid];
      dst[tid + 256] = src[tid + 256];
    }
    __syncthreads();
    bf16x8 af[4], bfr[4];
#pragma unroll
    for (int mt = 0; mt < 4; mt++)
      af[mt] = *(const bf16x8*)(&lA[(wm * 4 + mt) * 512 + l * 8]);
#pragma unroll
    for (int nt = 0; nt < 4; nt++)
      bfr[nt] = *(const bf16x8*)(&lB[(wn * 4 + nt) * 512 + l * 8]);
#pragma unroll
    for (int mt = 0; mt < 4; mt++)
#pragma unroll
      for (int nt = 0; nt < 4; nt++)
        acc[mt][nt] = __builtin_amdgcn_mfma_f32_16x16x32_bf16(af[mt], bfr[nt],
                                                              acc[mt][nt], 0, 0, 0);
    __syncthreads();
  }
  // epilogue: C/D layout col=lane&15, row=(lane>>4)*4+j  [verified m89/m91]
#pragma unroll
  for (int nt = 0; nt < 4; nt++) {
    int n = n0 + wn * 64 + nt * 16 + (l & 15);
    float bv = bias[n];
#pragma unroll
    for (int mt = 0; mt < 4; mt++) {
#pragma unroll
      for (int j = 0; j < 4; j++) {
        int row = m0 + wm * 64 + mt * 16 + ((l >> 4) << 2) + j;
        float v = acc[mt][nt][j] + bv;
        if (RELU) v = fmaxf(v, 0.f);
        if (WF32) Cf[(long)row * N + n] = v;
        if (WBF16) Cb[(long)row * N + n] = (bf16)v;
      }
    }
  }
}

// ---------------------------------------------------------------- relw ----
// Fused relation-projection + attention scores.
// Block = one (t1, t2-pair): 64 rows of relation (2 t2 x 32 b), 8 waves.
// Wave h owns head h: accumulates ra (cols h*64..) and rb (cols 512+h*64..).
// After the K loop, p = (q+ra+ba)*(k+rb+bb) is lane-local; reduce over dh
// (4 n-tiles in-register + shfl_xor over the 16 col-lanes) -> w.
// w stored transposed: wT[i][bh][j=t1] (contiguous j for the softmax kernel).
__global__ __launch_bounds__(512, 2) void relw_kernel(
    const float* __restrict__ rel, const bf16* __restrict__ relw_fl,
    const float* __restrict__ rel_b, const float* __restrict__ qkv,
    float* __restrict__ wT) {
  __shared__ bf16 lA[2][2048];  // double-buffered 4KB A tile (64x32 bf16, frag-linear)
  const int tid = threadIdx.x;
  const int l = tid & 63;
  const int h = tid >> 6;
  const int t1 = blockIdx.x >> 5;
  const int r2 = blockIdx.x & 31;               // t2 pair index
  const long row0 = ((long)t1 * 64 + r2 * 2) * 32;  // first global row (t1,t2,b) flat

  f32x4 acc[4][8];
#pragma unroll
  for (int i = 0; i < 4; i++)
#pragma unroll
    for (int j = 0; j < 8; j++) acc[i][j] = (f32x4)0.f;

  // staging map: thread t -> row sr=t>>3, k-group sg=t&7 (4 fp32 elems)
  const int sr = tid >> 3;
  const int sg = tid & 7;
  const int smt = sr >> 4;
  const int slane = ((sg >> 1) << 4) + (sr & 15);
  const int sdst = smt * 512 + slane * 8 + (sg & 1) * 4;  // bf16 elems
  const float* srcbase = rel + (row0 + sr) * 512 + sg * 4;

  f32x4 stg = *(const f32x4*)(srcbase);
  for (int kt = 0; kt < 16; ++kt) {
    const int buf = kt & 1;
    bf16x4 cv;
#pragma unroll
    for (int u = 0; u < 4; ++u) cv[u] = (bf16)stg[u];
    *(bf16x4*)(&lA[buf][sdst]) = cv;
    f32x4 stg_next = stg;
    if (kt < 15) stg_next = *(const f32x4*)(srcbase + (kt + 1) * 32);
    __syncthreads();

    bf16x8 af[4];
#pragma unroll
    for (int mt = 0; mt < 4; mt++)
      af[mt] = *(const bf16x8*)(&lA[buf][mt * 512 + l * 8]);
    const bf16* bbase = relw_fl + ((long)kt * 64 + h * 4) * 512 + l * 8;
    bf16x8 bfr[8];
#pragma unroll
    for (int nt = 0; nt < 4; nt++) {
      bfr[nt] = *(const bf16x8*)(bbase + nt * 512);            // ra frags
      bfr[4 + nt] = *(const bf16x8*)(bbase + 16384 + nt * 512); // rb frags (+32 frags)
    }
#pragma unroll
    for (int mt = 0; mt < 4; mt++)
#pragma unroll
      for (int ns = 0; ns < 8; ns++)
        acc[mt][ns] = __builtin_amdgcn_mfma_f32_16x16x32_bf16(af[mt], bfr[ns],
                                                              acc[mt][ns], 0, 0, 0);
    stg = stg_next;
  }

  // epilogue: w[i=t2, j=t1, bh] = (1/64) * sum_dh (q+ra)(k+rb)
  const int dhb = h * 64;
#pragma unroll
  for (int mt = 0; mt < 4; mt++) {
    float psum[4] = {0.f, 0.f, 0.f, 0.f};
#pragma unroll
    for (int nt = 0; nt < 4; nt++) {
      const int dh = nt * 16 + (l & 15);
      const float ba = rel_b[dhb + dh];
      const float bb2 = rel_b[512 + dhb + dh];
#pragma unroll
      for (int j = 0; j < 4; j++) {
        int rl = mt * 16 + ((l >> 4) << 2) + j;
        int b = rl & 31;
        int t2 = r2 * 2 + (rl >> 5);
        float qv = qkv[(long)(t2 * 32 + b) * 1536 + dhb + dh];
        float kv = qkv[(long)(t1 * 32 + b) * 1536 + 512 + dhb + dh];
        psum[j] += (qv + acc[mt][nt][j] + ba) * (kv + acc[mt][nt + 4][j] + bb2);
      }
    }
#pragma unroll
    for (int j = 0; j < 4; j++) {
      float v = psum[j];
      v += __shfl_xor(v, 1);
      v += __shfl_xor(v, 2);
      v += __shfl_xor(v, 4);
      v += __shfl_xor(v, 8);
      if ((l & 15) == 0) {
        int rl = mt * 16 + ((l >> 4) << 2) + j;
        int b = rl & 31;
        int i = r2 * 2 + (rl >> 5);
        wT[(long)(i * 256 + b * 8 + h) * 64 + t1] = v * 0.015625f;
      }
    }
  }
}

// ---------------------------------------------------------------- attn ----
// One wave per (i, bh): softmax over j (64 lanes) then attn = sum_j p_j * v_j.
__global__ __launch_bounds__(256) void attn_kernel(const float* __restrict__ wT,
                                                   const float* __restrict__ qkv,
                                                   bf16* __restrict__ attn_b) {
  const int l = threadIdx.x & 63;
  const int g = blockIdx.x * 4 + (threadIdx.x >> 6);
  const int bh = g & 255;
  const int i = g >> 8;
  const int b = bh >> 3, h = bh & 7;
  float wv = wT[(long)g * 64 + l];
  float m = wv;
#pragma unroll
  for (int s = 1; s < 64; s <<= 1) m = fmaxf(m, __shfl_xor(m, s));
  float e = __expf(wv - m);
  float ssum = e;
#pragma unroll
  for (int s = 1; s < 64; s <<= 1) ssum += __shfl_xor(ssum, s);
  float p = e / ssum;
  float acc = 0.f;
  const float* vbase = qkv + 1024 + (long)b * 1536 + h * 64 + l;
#pragma unroll 8
  for (int j = 0; j < 64; ++j) {
    float pj = __shfl(p, j);
    acc = fmaf(pj, vbase[(long)j * 49152], acc);
  }
  attn_b[(long)(i * 32 + b) * 512 + h * 64 + l] = (bf16)acc;
}

// ------------------------------------------------------------------ ln ----
// One wave per row of 512. out = LN(a + res) * g + b; optional bf16 copy.
template <bool WB>
__global__ __launch_bounds__(256) void ln_kernel(const float* __restrict__ a,
                                                 const float* __restrict__ res,
                                                 const float* __restrict__ g,
                                                 const float* __restrict__ bb,
                                                 float* __restrict__ of,
                                                 bf16* __restrict__ ob) {
  const int l = threadIdx.x & 63;
  const int row = blockIdx.x * 4 + (threadIdx.x >> 6);
  const float* pa = a + (long)row * 512;
  const float* pr = res + (long)row * 512;
  float xv[8];
  float s = 0.f, sq = 0.f;
#pragma unroll
  for (int u = 0; u < 8; ++u) {
    xv[u] = pa[u * 64 + l] + pr[u * 64 + l];
    s += xv[u];
    sq += xv[u] * xv[u];
  }
#pragma unroll
  for (int st = 1; st < 64; st <<= 1) {
    s += __shfl_xor(s, st);
    sq += __shfl_xor(sq, st);
  }
  float mean = s * (1.f / 512.f);
  float var = sq * (1.f / 512.f) - mean * mean;
  float rstd = rsqrtf(var + 1e-5f);
#pragma unroll
  for (int u = 0; u < 8; ++u) {
    int e = u * 64 + l;
    float v = (xv[u] - mean) * rstd * g[e] + bb[e];
    of[(long)row * 512 + e] = v;
    if (WB) ob[(long)row * 512 + e] = (bf16)v;
  }
}

// -------------------------------------------------------------- launch ----
extern "C" void kernel_launch(void* const* d_in, const int* in_sizes, int n_in,
                              void* d_out, int out_size, void* d_ws, size_t ws_size,
                              hipStream_t stream) {
  const float* x     = (const float*)d_in[0];
  const float* rel   = (const float*)d_in[1];
  const float* in_w  = (const float*)d_in[2];
  const float* in_b  = (const float*)d_in[3];
  const float* rel_w = (const float*)d_in[4];
  const float* rel_b = (const float*)d_in[5];
  const float* out_w = (const float*)d_in[6];
  const float* out_b = (const float*)d_in[7];
  const float* fc1_w = (const float*)d_in[8];
  const float* fc1_b = (const float*)d_in[9];
  const float* fc2_w = (const float*)d_in[10];
  const float* fc2_b = (const float*)d_in[11];
  const float* ln1_g = (const float*)d_in[12];
  const float* ln1_b = (const float*)d_in[13];
  const float* ln2_g = (const float*)d_in[14];
  const float* ln2_b = (const float*)d_in[15];

  char* ws = (char*)d_ws;
  float* qkv   = (float*)(ws + 0);          // 12,582,912 B
  bf16* x_b    = (bf16*)(ws + 12582912);    //  2,097,152
  bf16* inw    = (bf16*)(ws + 14680064);    //  1,572,864
  bf16* relwB  = (bf16*)(ws + 16252928);    //  1,048,576
  bf16* outwB  = (bf16*)(ws + 17301504);    //    524,288
  bf16* fc1wB  = (bf16*)(ws + 17825792);    //  2,097,152
  bf16* fc2wB  = (bf16*)(ws + 19922944);    //  2,097,152
  float* wT    = (float*)(ws + 22020096);   //  4,194,304
  bf16* attn   = (bf16*)(ws + 26214400);    //  2,097,152
  float* opre  = (float*)(ws + 28311552);   //  4,194,304
  float* hf    = (float*)(ws + 32505856);   //  4,194,304
  bf16* hb     = (bf16*)(ws + 36700160);    //  2,097,152
  bf16* fb     = (bf16*)(ws + 38797312);    //  8,388,608
  float* f2o   = (float*)(ws + 47185920);   //  4,194,304  -> total 51,380,224 B

  prep_kernel<<<18432, 256, 0, stream>>>(x, in_w, rel_w, out_w, fc1_w, fc2_w,
                                         x_b, inw, relwB, outwB, fc1wB, fc2wB);
  gemm_bf16<false, true, false><<<dim3(16, 12), 256, 0, stream>>>(
      x_b, inw, in_b, qkv, nullptr, 2048, 1536, 512);
  relw_kernel<<<2048, 512, 0, stream>>>(rel, relwB, rel_b, qkv, wT);
  attn_kernel<<<4096, 256, 0, stream>>>(wT, qkv, attn);
  gemm_bf16<false, true, false><<<dim3(16, 4), 256, 0, stream>>>(
      attn, outwB, out_b, opre, nullptr, 2048, 512, 512);
  ln_kernel<true><<<512, 256, 0, stream>>>(opre, x, ln1_g, ln1_b, hf, hb);
  gemm_bf16<true, false, true><<<dim3(16, 16), 256, 0, stream>>>(
      hb, fc1wB, fc1_b, nullptr, fb, 2048, 2048, 512);
  gemm_bf16<false, true, false><<<dim3(16, 4), 256, 0, stream>>>(
      fb, fc2wB, fc2_b, f2o, nullptr, 2048, 512, 2048);
  ln_kernel<false><<<512, 256, 0, stream>>>(f2o, hf, ln2_g, ln2_b, (float*)d_out,
                                            nullptr);
}

// Round 3
// 648.941 us; speedup vs baseline: 1.0474x; 1.0474x over previous
//
#include <hip/hip_runtime.h>

// GraphTransformerLayer fused pipeline for MI355X (gfx950).
// T=64, B=32, E=512, F=2048, H=8, Dh=64, TB=2048 rows.

typedef __bf16 bf16;
typedef __attribute__((ext_vector_type(8))) __bf16 bf16x8;
typedef __attribute__((ext_vector_type(4))) __bf16 bf16x4;
typedef __attribute__((ext_vector_type(4))) float f32x4;

__device__ __forceinline__ void gl_lds16(const bf16* g, bf16* l) {
  __builtin_amdgcn_global_load_lds((const __attribute__((address_space(1))) void*)g,
                                   (__attribute__((address_space(3))) void*)l, 16, 0, 0);
}

// Raw barrier: drain only LDS ops (not vmcnt) so register prefetches stay in flight.
__device__ __forceinline__ void block_sync_lds() {
  asm volatile("s_waitcnt lgkmcnt(0)" ::: "memory");
  __builtin_amdgcn_s_barrier();
  asm volatile("" ::: "memory");
}

// ---------------------------------------------------------------- prep ----
// Fragment-linear layout for a (K,N) operand B[k][n]:
//   elem d: frag=d>>9, lane=(d>>3)&63, j=d&7; kt=frag/NT, nt=frag%NT;
//   k = kt*32 + (lane>>4)*8 + j, n = nt*16 + (lane&15).
//   => offset within frag for (kl=k&31, nl=n&15): (kl>>3)*128 + nl*8 + (kl&7)

template <int NSRC, int NT>
__device__ __forceinline__ void convkn(int t, const float* __restrict__ W,
                                       bf16* __restrict__ dst) {
  int frag = t >> 5, r = t & 31;
  int lh = r >> 3, j = r & 7;   // kl = lh*8 + j
  int kt = frag / NT, nt = frag - kt * NT;
  int k = kt * 32 + lh * 8 + j;
  const float* src = W + (long)k * NSRC + nt * 16;
  f32x4 v0 = ((const f32x4*)src)[0], v1 = ((const f32x4*)src)[1];
  f32x4 v2 = ((const f32x4*)src)[2], v3 = ((const f32x4*)src)[3];
  bf16* d = dst + frag * 512 + lh * 128 + j;  // FIX: + lh*128 (k-subgroup)
  d[0] = (bf16)v0[0];  d[8] = (bf16)v0[1];  d[16] = (bf16)v0[2];  d[24] = (bf16)v0[3];
  d[32] = (bf16)v1[0]; d[40] = (bf16)v1[1]; d[48] = (bf16)v1[2];  d[56] = (bf16)v1[3];
  d[64] = (bf16)v2[0]; d[72] = (bf16)v2[1]; d[80] = (bf16)v2[2];  d[88] = (bf16)v2[3];
  d[96] = (bf16)v3[0]; d[104] = (bf16)v3[1]; d[112] = (bf16)v3[2]; d[120] = (bf16)v3[3];
}

__global__ void prep_kernel(const float* __restrict__ x,
                            const float* __restrict__ in_w,
                            const float* __restrict__ rel_w,
                            const float* __restrict__ out_w,
                            const float* __restrict__ fc1_w,
                            const float* __restrict__ fc2_w,
                            bf16* __restrict__ x_b,
                            bf16* __restrict__ inw_fl,
                            bf16* __restrict__ relw_fl,
                            bf16* __restrict__ outw_fl,
                            bf16* __restrict__ fc1w_fl,
                            bf16* __restrict__ fc2w_fl) {
  int t = blockIdx.x * 256 + threadIdx.x;
  if (t < 131072) {  // x -> bf16, 8/thread
    int d0 = t * 8;
    f32x4 a = *(const f32x4*)(x + d0), b = *(const f32x4*)(x + d0 + 4);
    bf16x8 r;
    r[0] = (bf16)a[0]; r[1] = (bf16)a[1]; r[2] = (bf16)a[2]; r[3] = (bf16)a[3];
    r[4] = (bf16)b[0]; r[5] = (bf16)b[1]; r[6] = (bf16)b[2]; r[7] = (bf16)b[3];
    *(bf16x8*)(x_b + d0) = r;
    return;
  }
  t -= 131072;
  if (t < 98304) {  // in_w (n,k) row-major: B[k][n]=in_w[n*512+k]; k-contig reads
    int d0 = t * 8;
    int frag = d0 >> 9, l = t & 63;
    int kt = frag / 96, nt = frag - kt * 96;
    const float* src = in_w + (long)(nt * 16 + (l & 15)) * 512 + kt * 32 + ((l >> 4) << 3);
    f32x4 a = *(const f32x4*)src, b = *(const f32x4*)(src + 4);
    bf16x8 r;
    r[0] = (bf16)a[0]; r[1] = (bf16)a[1]; r[2] = (bf16)a[2]; r[3] = (bf16)a[3];
    r[4] = (bf16)b[0]; r[5] = (bf16)b[1]; r[6] = (bf16)b[2]; r[7] = (bf16)b[3];
    *(bf16x8*)(inw_fl + d0) = r;
    return;
  }
  t -= 98304;
  if (t < 32768) { convkn<1024, 64>(t, rel_w, relw_fl); return; }
  t -= 32768;
  if (t < 16384) { convkn<512, 32>(t, out_w, outw_fl); return; }
  t -= 16384;
  if (t < 65536) { convkn<2048, 128>(t, fc1_w, fc1w_fl); return; }
  t -= 65536;
  if (t < 65536) { convkn<512, 32>(t, fc2_w, fc2w_fl); }
}

// ---------------------------------------------------------------- gemm ----
// Generic bf16 MFMA GEMM, tile (WM*MT*16) x (WN*NT*16), BK=32, 4 waves.
// Double-buffered LDS via global_load_lds; stage(kt+1) issued AFTER barrier
// so loads overlap the MFMA phase; one barrier per K-step.
template <int WM, int WN, int MT, int NT, bool RELU, bool WF32, bool WBF16>
__global__ __launch_bounds__(256, 2) void gemm_bf16(
    const bf16* __restrict__ A, const bf16* __restrict__ Bfl,
    const float* __restrict__ bias, float* __restrict__ Cf,
    bf16* __restrict__ Cb, int M, int N, int K) {
  constexpr int AFR = WM * MT;  // A frags (16-row each)
  constexpr int BFR = WN * NT;
  constexpr int NA = AFR / 4, NB = BFR / 4;
  __shared__ __align__(16) bf16 lA[2][AFR * 512];
  __shared__ __align__(16) bf16 lB[2][BFR * 512];
  const int tid = threadIdx.x, l = tid & 63, wv = tid >> 6;
  const int wm = wv / WN, wn = wv % WN;
  const int m0 = blockIdx.x * (AFR * 16), n0 = blockIdx.y * (BFR * 16);
  const int NTfr = N >> 4, nb0 = n0 >> 4, KT = K >> 5;

  f32x4 acc[MT][NT];
#pragma unroll
  for (int i = 0; i < MT; i++)
#pragma unroll
    for (int j = 0; j < NT; j++) acc[i][j] = (f32x4)0.f;

  const bf16* pA[NA];
#pragma unroll
  for (int i = 0; i < NA; ++i) {
    int f = wv + i * 4;
    pA[i] = A + (long)(m0 + f * 16 + (l & 15)) * K + ((l >> 4) << 3);
  }
  const bf16* pB[NB];
#pragma unroll
  for (int i = 0; i < NB; ++i) {
    int f = wv + i * 4;
    pB[i] = Bfl + (long)(nb0 + f) * 512 + l * 8;
  }
  // prologue: stage kt=0 into buf 0
#pragma unroll
  for (int i = 0; i < NA; ++i) gl_lds16(pA[i], &lA[0][(wv + i * 4) * 512]);
#pragma unroll
  for (int i = 0; i < NB; ++i) gl_lds16(pB[i], &lB[0][(wv + i * 4) * 512]);

  for (int kt = 0; kt < KT; ++kt) {
    const int buf = kt & 1;
    __syncthreads();  // drains stage(kt) (vmcnt) + prior-step LDS reads
    if (kt + 1 < KT) {
#pragma unroll
      for (int i = 0; i < NA; ++i)
        gl_lds16(pA[i] + (kt + 1) * 32, &lA[buf ^ 1][(wv + i * 4) * 512]);
#pragma unroll
      for (int i = 0; i < NB; ++i)
        gl_lds16(pB[i] + (long)(kt + 1) * NTfr * 512, &lB[buf ^ 1][(wv + i * 4) * 512]);
    }
    bf16x8 af[MT], bfr[NT];
#pragma unroll
    for (int mt = 0; mt < MT; ++mt)
      af[mt] = *(const bf16x8*)(&lA[buf][(wm * MT + mt) * 512 + l * 8]);
#pragma unroll
    for (int nt = 0; nt < NT; ++nt)
      bfr[nt] = *(const bf16x8*)(&lB[buf][(wn * NT + nt) * 512 + l * 8]);
#pragma unroll
    for (int mt = 0; mt < MT; ++mt)
#pragma unroll
      for (int nt = 0; nt < NT; ++nt)
        acc[mt][nt] = __builtin_amdgcn_mfma_f32_16x16x32_bf16(af[mt], bfr[nt],
                                                              acc[mt][nt], 0, 0, 0);
  }
  // epilogue: C/D layout col=lane&15, row=(lane>>4)*4+j
#pragma unroll
  for (int nt = 0; nt < NT; nt++) {
    int n = n0 + (wn * NT + nt) * 16 + (l & 15);
    float bv = bias[n];
#pragma unroll
    for (int mt = 0; mt < MT; mt++) {
#pragma unroll
      for (int j = 0; j < 4; j++) {
        int row = m0 + (wm * MT + mt) * 16 + ((l >> 4) << 2) + j;
        float v = acc[mt][nt][j] + bv;
        if (RELU) v = fmaxf(v, 0.f);
        if (WF32) Cf[(long)row * N + n] = v;
        if (WBF16) Cb[(long)row * N + n] = (bf16)v;
      }
    }
  }
}

// ---------------------------------------------------------------- relw ----
// Fused relation-projection + attention scores. Block = (t1, t2-pair): 64 rows,
// 8 waves; wave h owns head h (ra cols h*64.., rb cols 512+h*64..).
// Pipelined: raw s_barrier (lgkm-only drain), B-frags reg double-buffered
// (prefetch kt+1 during kt's MFMAs), A prefetched 2 steps ahead, LDS A dbuf.
#define RELW_STEP(kt_, buf_, BC, BN, STG_W, STG_P)                               \
  {                                                                              \
    bf16x4 cv;                                                                   \
    cv[0] = (bf16)STG_W[0]; cv[1] = (bf16)STG_W[1];                              \
    cv[2] = (bf16)STG_W[2]; cv[3] = (bf16)STG_W[3];                              \
    *(bf16x4*)(&lA[buf_][adst]) = cv;                                            \
    block_sync_lds();                                                            \
    if ((kt_) + 2 < 16) STG_P = *(const f32x4*)(asrc + ((kt_) + 2) * 32);        \
    if ((kt_) + 1 < 16) {                                                        \
      _Pragma("unroll") for (int f = 0; f < 8; ++f)                              \
          BN[f] = *(const bf16x8*)(relw_fl + (long)((kt_) + 1) * 32768 + boff0 + \
                                   (((f >> 2) * 32 + (f & 3)) << 9));            \
    }                                                                            \
    bf16x8 af[4];                                                                \
    _Pragma("unroll") for (int mt = 0; mt < 4; mt++)                             \
        af[mt] = *(const bf16x8*)(&lA[buf_][mt * 512 + l * 8]);                  \
    _Pragma("unroll") for (int mt = 0; mt < 4; mt++)                             \
        _Pragma("unroll") for (int ns = 0; ns < 8; ns++)                         \
            acc[mt][ns] = __builtin_amdgcn_mfma_f32_16x16x32_bf16(               \
                af[mt], BC[ns], acc[mt][ns], 0, 0, 0);                           \
  }

__global__ __launch_bounds__(512, 2) void relw_kernel(
    const float* __restrict__ rel, const bf16* __restrict__ relw_fl,
    const float* __restrict__ rel_b, const float* __restrict__ qkv,
    float* __restrict__ wT) {
  __shared__ __align__(16) bf16 lA[2][2048];
  const int tid = threadIdx.x;
  const int l = tid & 63;
  const int h = tid >> 6;
  const int t1 = blockIdx.x >> 5;
  const int r2 = blockIdx.x & 31;
  const long row0 = ((long)t1 * 64 + r2 * 2) * 32;

  f32x4 acc[4][8];
#pragma unroll
  for (int i = 0; i < 4; i++)
#pragma unroll
    for (int j = 0; j < 8; j++) acc[i][j] = (f32x4)0.f;

  // A staging: slot=tid>>1 (256 slots of 8 elems), half=tid&1 (4 elems each)
  const int slot = tid >> 1, half = tid & 1;
  const int fA = slot >> 6, l2 = slot & 63;
  const float* asrc =
      rel + (row0 + fA * 16 + (l2 & 15)) * 512 + ((l2 >> 4) << 3) + half * 4;
  const int adst = fA * 512 + l2 * 8 + half * 4;

  const int boff0 = h * 2048 + l * 8;  // wave-h B base (elems)

  f32x4 stgA = *(const f32x4*)asrc;
  f32x4 stgB = *(const f32x4*)(asrc + 32);
  bf16x8 b0[8], b1[8];
#pragma unroll
  for (int f = 0; f < 8; ++f)
    b0[f] = *(const bf16x8*)(relw_fl + boff0 + (((f >> 2) * 32 + (f & 3)) << 9));

  for (int kt = 0; kt < 16; kt += 2) {
    RELW_STEP(kt, 0, b0, b1, stgA, stgA)
    RELW_STEP(kt + 1, 1, b1, b0, stgB, stgB)
  }

  // epilogue: w[i=t2, j=t1, bh] = (1/64) * sum_dh (q+ra+ba)(k+rb+bb)
  const int dhb = h * 64;
#pragma unroll
  for (int mt = 0; mt < 4; mt++) {
    float psum[4] = {0.f, 0.f, 0.f, 0.f};
#pragma unroll
    for (int nt = 0; nt < 4; nt++) {
      const int dh = nt * 16 + (l & 15);
      const float ba = rel_b[dhb + dh];
      const float bb2 = rel_b[512 + dhb + dh];
#pragma unroll
      for (int j = 0; j < 4; j++) {
        int rl = mt * 16 + ((l >> 4) << 2) + j;
        int b = rl & 31;
        int t2 = r2 * 2 + (rl >> 5);
        float qv = qkv[(long)(t2 * 32 + b) * 1536 + dhb + dh];
        float kv = qkv[(long)(t1 * 32 + b) * 1536 + 512 + dhb + dh];
        psum[j] += (qv + acc[mt][nt][j] + ba) * (kv + acc[mt][nt + 4][j] + bb2);
      }
    }
#pragma unroll
    for (int j = 0; j < 4; j++) {
      float v = psum[j];
      v += __shfl_xor(v, 1);
      v += __shfl_xor(v, 2);
      v += __shfl_xor(v, 4);
      v += __shfl_xor(v, 8);
      if ((l & 15) == 0) {
        int rl = mt * 16 + ((l >> 4) << 2) + j;
        int b = rl & 31;
        int i = r2 * 2 + (rl >> 5);
        wT[(long)(i * 256 + b * 8 + h) * 64 + t1] = v * 0.015625f;
      }
    }
  }
}

// ---------------------------------------------------------------- attn ----
// Block per (b,h): softmax over j then out[i,:] = sum_j p[i,j] v[j,:],
// all through LDS (v read once per block, no serial lane loop).
__global__ __launch_bounds__(256) void attn_kernel(const float* __restrict__ wT,
                                                   const float* __restrict__ qkv,
                                                   bf16* __restrict__ attn_b) {
  __shared__ __align__(16) float s[64][68];
  __shared__ __align__(16) float vl[64][68];
  __shared__ float pm[64][4], ps[64][4];
  const int tid = threadIdx.x;
  const int b = blockIdx.x >> 3, h = blockIdx.x & 7;
  const int i = tid >> 2, g = tid & 3;

  const float* wsrc = wT + ((long)i * 256 + b * 8 + h) * 64 + g * 16;
  f32x4 w0 = ((const f32x4*)wsrc)[0], w1 = ((const f32x4*)wsrc)[1];
  f32x4 w2 = ((const f32x4*)wsrc)[2], w3 = ((const f32x4*)wsrc)[3];
  const float* vsrc = qkv + ((long)i * 32 + b) * 1536 + 1024 + h * 64 + g * 16;
  f32x4 v0 = ((const f32x4*)vsrc)[0], v1 = ((const f32x4*)vsrc)[1];
  f32x4 v2 = ((const f32x4*)vsrc)[2], v3 = ((const f32x4*)vsrc)[3];
  *(f32x4*)&vl[i][g * 16] = v0;
  *(f32x4*)&vl[i][g * 16 + 4] = v1;
  *(f32x4*)&vl[i][g * 16 + 8] = v2;
  *(f32x4*)&vl[i][g * 16 + 12] = v3;
  float pmax = -1e30f;
#pragma unroll
  for (int u = 0; u < 4; ++u) {
    pmax = fmaxf(pmax, fmaxf(fmaxf(w0[u], w1[u]), fmaxf(w2[u], w3[u])));
  }
  pm[i][g] = pmax;
  __syncthreads();
  float m = fmaxf(fmaxf(pm[i][0], pm[i][1]), fmaxf(pm[i][2], pm[i][3]));
  float psum = 0.f;
  f32x4 e0, e1, e2, e3;
#pragma unroll
  for (int u = 0; u < 4; ++u) {
    e0[u] = __expf(w0[u] - m); psum += e0[u];
    e1[u] = __expf(w1[u] - m); psum += e1[u];
    e2[u] = __expf(w2[u] - m); psum += e2[u];
    e3[u] = __expf(w3[u] - m); psum += e3[u];
  }
  *(f32x4*)&s[i][g * 16] = e0;
  *(f32x4*)&s[i][g * 16 + 4] = e1;
  *(f32x4*)&s[i][g * 16 + 8] = e2;
  *(f32x4*)&s[i][g * 16 + 12] = e3;
  ps[i][g] = psum;
  __syncthreads();
  float scale = 1.f / (ps[i][0] + ps[i][1] + ps[i][2] + ps[i][3]);
  f32x4 o0 = (f32x4)0.f, o1 = (f32x4)0.f, o2 = (f32x4)0.f, o3 = (f32x4)0.f;
  for (int j = 0; j < 64; ++j) {
    float pj = s[i][j];
    const float* vr = &vl[j][g * 16];
    f32x4 a0 = ((const f32x4*)vr)[0], a1 = ((const f32x4*)vr)[1];
    f32x4 a2 = ((const f32x4*)vr)[2], a3 = ((const f32x4*)vr)[3];
#pragma unroll
    for (int u = 0; u < 4; ++u) {
      o0[u] = fmaf(pj, a0[u], o0[u]);
      o1[u] = fmaf(pj, a1[u], o1[u]);
      o2[u] = fmaf(pj, a2[u], o2[u]);
      o3[u] = fmaf(pj, a3[u], o3[u]);
    }
  }
  bf16x8 r0, r1;
#pragma unroll
  for (int u = 0; u < 4; ++u) {
    r0[u] = (bf16)(o0[u] * scale);
    r0[4 + u] = (bf16)(o1[u] * scale);
    r1[u] = (bf16)(o2[u] * scale);
    r1[4 + u] = (bf16)(o3[u] * scale);
  }
  bf16* dst = attn_b + ((long)i * 32 + b) * 512 + h * 64 + g * 16;
  *(bf16x8*)dst = r0;
  *(bf16x8*)(dst + 8) = r1;
}

// ------------------------------------------------------------------ ln ----
template <bool WB>
__global__ __launch_bounds__(256) void ln_kernel(const float* __restrict__ a,
                                                 const float* __restrict__ res,
                                                 const float* __restrict__ g,
                                                 const float* __restrict__ bb,
                                                 float* __restrict__ of,
                                                 bf16* __restrict__ ob) {
  const int l = threadIdx.x & 63;
  const int row = blockIdx.x * 4 + (threadIdx.x >> 6);
  const float* pa = a + (long)row * 512;
  const float* pr = res + (long)row * 512;
  float xv[8];
  float s = 0.f, sq = 0.f;
#pragma unroll
  for (int u = 0; u < 8; ++u) {
    xv[u] = pa[u * 64 + l] + pr[u * 64 + l];
    s += xv[u];
    sq += xv[u] * xv[u];
  }
#pragma unroll
  for (int st = 1; st < 64; st <<= 1) {
    s += __shfl_xor(s, st);
    sq += __shfl_xor(sq, st);
  }
  float mean = s * (1.f / 512.f);
  float var = sq * (1.f / 512.f) - mean * mean;
  float rstd = rsqrtf(var + 1e-5f);
#pragma unroll
  for (int u = 0; u < 8; ++u) {
    int e = u * 64 + l;
    float v = (xv[u] - mean) * rstd * g[e] + bb[e];
    of[(long)row * 512 + e] = v;
    if (WB) ob[(long)row * 512 + e] = (bf16)v;
  }
}

// -------------------------------------------------------------- launch ----
extern "C" void kernel_launch(void* const* d_in, const int* in_sizes, int n_in,
                              void* d_out, int out_size, void* d_ws, size_t ws_size,
                              hipStream_t stream) {
  const float* x     = (const float*)d_in[0];
  const float* rel   = (const float*)d_in[1];
  const float* in_w  = (const float*)d_in[2];
  const float* in_b  = (const float*)d_in[3];
  const float* rel_w = (const float*)d_in[4];
  const float* rel_b = (const float*)d_in[5];
  const float* out_w = (const float*)d_in[6];
  const float* out_b = (const float*)d_in[7];
  const float* fc1_w = (const float*)d_in[8];
  const float* fc1_b = (const float*)d_in[9];
  const float* fc2_w = (const float*)d_in[10];
  const float* fc2_b = (const float*)d_in[11];
  const float* ln1_g = (const float*)d_in[12];
  const float* ln1_b = (const float*)d_in[13];
  const float* ln2_g = (const float*)d_in[14];
  const float* ln2_b = (const float*)d_in[15];

  char* ws = (char*)d_ws;
  float* qkv   = (float*)(ws + 0);          // 12,582,912 B
  bf16* x_b    = (bf16*)(ws + 12582912);    //  2,097,152
  bf16* inw    = (bf16*)(ws + 14680064);    //  1,572,864
  bf16* relwB  = (bf16*)(ws + 16252928);    //  1,048,576
  bf16* outwB  = (bf16*)(ws + 17301504);    //    524,288
  bf16* fc1wB  = (bf16*)(ws + 17825792);    //  2,097,152
  bf16* fc2wB  = (bf16*)(ws + 19922944);    //  2,097,152
  float* wT    = (float*)(ws + 22020096);   //  4,194,304
  bf16* attn   = (bf16*)(ws + 26214400);    //  2,097,152
  float* opre  = (float*)(ws + 28311552);   //  4,194,304
  float* hf    = (float*)(ws + 32505856);   //  4,194,304
  bf16* hb     = (bf16*)(ws + 36700160);    //  2,097,152
  bf16* fb     = (bf16*)(ws + 38797312);    //  8,388,608
  float* f2o   = (float*)(ws + 47185920);   //  4,194,304

  prep_kernel<<<1600, 256, 0, stream>>>(x, in_w, rel_w, out_w, fc1_w, fc2_w,
                                        x_b, inw, relwB, outwB, fc1wB, fc2wB);
  gemm_bf16<2, 2, 2, 4, false, true, false><<<dim3(32, 12), 256, 0, stream>>>(
      x_b, inw, in_b, qkv, nullptr, 2048, 1536, 512);
  relw_kernel<<<2048, 512, 0, stream>>>(rel, relwB, rel_b, qkv, wT);
  attn_kernel<<<256, 256, 0, stream>>>(wT, qkv, attn);
  gemm_bf16<2, 2, 2, 2, false, true, false><<<dim3(32, 8), 256, 0, stream>>>(
      attn, outwB, out_b, opre, nullptr, 2048, 512, 512);
  ln_kernel<true><<<512, 256, 0, stream>>>(opre, x, ln1_g, ln1_b, hf, hb);
  gemm_bf16<2, 2, 4, 4, true, false, true><<<dim3(16, 16), 256, 0, stream>>>(
      hb, fc1wB, fc1_b, nullptr, fb, 2048, 2048, 512);
  gemm_bf16<2, 2, 2, 2, false, true, false><<<dim3(32, 8), 256, 0, stream>>>(
      fb, fc2wB, fc2_b, f2o, nullptr, 2048, 512, 2048);
  ln_kernel<false><<<512, 256, 0, stream>>>(f2o, hf, ln2_g, ln2_b, (float*)d_out,
                                            nullptr);
}